// Round 8
// baseline (230.272 us; speedup 1.0000x reference)
//
#include <hip/hip_runtime.h>
#include <math.h>

#define HH 160
#define WW 160
#define HWSZ 25600
#define TR 10
#define TC 22
#define NSLOT 220   // TR*TC tile slots, margin +-3 around 16x4 px tile

typedef __attribute__((ext_vector_type(8))) short short8;
typedef __attribute__((ext_vector_type(4))) short short4v;
typedef __attribute__((ext_vector_type(8))) _Float16 half8;
typedef __attribute__((ext_vector_type(2))) _Float16 half2v;
typedef __attribute__((ext_vector_type(4))) float f32x4;

__device__ __forceinline__ short f2h(float f) {
  union { _Float16 h; short s; } u; u.h = (_Float16)f; return u.s;
}
__device__ __forceinline__ float h2f(short s) {
  union { _Float16 h; short s; } u; u.s = s; return (float)u.h;
}
__device__ __forceinline__ half2v bcast_h(short s) {
  unsigned int x = (unsigned short)s; x |= x << 16;
  union { unsigned int u; half2v h; } v; v.u = x; return v.h;
}

// ---------------------------------------------------------------------------
// prep: BN fold + reorder+convert weights to f16 MFMA A-fragment layout.
// dcn:  [f18][ot4][m16][q4][j8] = w[ot*16+m][c*9+k], kp=f*32+q*8+j
// om:   [f18][ot2][m16][q4][j8], oc>=27 zero-padded
__global__ __launch_bounds__(256) void prep_kernel(
    const float* __restrict__ g1, const float* __restrict__ b1,
    const float* __restrict__ m1, const float* __restrict__ v1,
    const float* __restrict__ g2, const float* __restrict__ b2,
    const float* __restrict__ m2, const float* __restrict__ v2,
    const float* __restrict__ wd1, const float* __restrict__ wd2,
    const float* __restrict__ wo1, const float* __restrict__ wo2,
    float* __restrict__ sc, short* __restrict__ wd1h, short* __restrict__ wd2h,
    short* __restrict__ wo1h, short* __restrict__ wo2h) {
  int i0 = blockIdx.x * 256 + threadIdx.x;
  int stride = gridDim.x * 256;
  for (int i = i0; i < 36864; i += stride) {
    int j = i & 7, q = (i >> 3) & 3, m = (i >> 5) & 15;
    int ot = (i >> 9) & 3, f = i >> 11;
    int kp = f * 32 + q * 8 + j;
    int k = kp >> 6, c = kp & 63;
    int src = (ot * 16 + m) * 576 + c * 9 + k;
    wd1h[i] = f2h(wd1[src]);
    wd2h[i] = f2h(wd2[src]);
  }
  for (int i = i0; i < 18432; i += stride) {
    int j = i & 7, q = (i >> 3) & 3, m = (i >> 5) & 15;
    int ot = (i >> 9) & 1, f = i >> 10;
    int kp = f * 32 + q * 8 + j;
    int k = kp >> 6, c = kp & 63;
    int oc = ot * 16 + m;
    wo1h[i] = (oc < 27) ? f2h(wo1[oc * 576 + c * 9 + k]) : (short)0;
    wo2h[i] = (oc < 27) ? f2h(wo2[oc * 576 + c * 9 + k]) : (short)0;
  }
  if (i0 < 64) {
    float s1 = g1[i0] * rsqrtf(v1[i0] + 1e-5f);
    sc[i0]       = s1;
    sc[64 + i0]  = b1[i0] - m1[i0] * s1;
    float s2 = g2[i0] * rsqrtf(v2[i0] + 1e-5f);
    sc[128 + i0] = s2;
    sc[192 + i0] = b2[i0] - m2[i0] * s2;
  }
}

// ---------------------------------------------------------------------------
// xcl: transpose x f32 NCHW -> f16 NHWC (coalesced both sides via LDS tile)
__global__ __launch_bounds__(256) void xcl_kernel(
    const float* __restrict__ x, short* __restrict__ xcl) {
  __shared__ short tmp[64][72];
  int t = threadIdx.x;
  int p0 = blockIdx.x * 64;
  int b = blockIdx.y;
  const float* xb = x + (size_t)b * 64 * HWSZ;
  for (int i = t; i < 4096; i += 256) {
    int c = i >> 6, p = i & 63;
    tmp[p][c] = f2h(xb[c * HWSZ + p0 + p]);
  }
  __syncthreads();
  short* ob = xcl + ((size_t)b * HWSZ + p0) * 64;
  for (int i = t; i < 512; i += 256) {
    int p = i >> 3, g = i & 7;
    *(short8*)&ob[p * 64 + g * 8] = *(const short8*)&tmp[p][g * 8];
  }
}

// ---------------------------------------------------------------------------
// dcn_fused: offset-conv (27ch) + modulated deform conv (64->64) + BN
//            + optional residual + GELU, all from one staged tile.
// Block: 16x * 4y px, 256 thr / 4 waves. Wave w owns pixel row y0+w.
// A-weights read from global (L1-served, 8KB/tap working set) -> LDS pipe
// carries only xt/meta (R7's As round-trip saturated LDS at ~7k cyc/block).
// 38.6 KB LDS -> 4 blocks/CU for latency hiding; no barriers in main loop.
__global__ __launch_bounds__(256, 4) void dcn_fused(
    const short* __restrict__ xcl,     // [B][HW][64] f16 NHWC
    const short* __restrict__ who,     // om weights  [f][2][16][4][8]
    const float* __restrict__ bias_om, // 27
    const short* __restrict__ whd,     // dcn weights [f][4][16][4][8]
    const float* __restrict__ scale, const float* __restrict__ shift,
    const float* __restrict__ identity,  // f32 NCHW or null
    short* __restrict__ out_cl,          // f16 NHWC (layer 1) or null
    float* __restrict__ out_f32) {       // f32 NCHW (layer 2) or null
  __shared__ short xt[NSLOT * 64];          // 28.2 KB, 16B groups swizzled
  __shared__ short omv[64 * 36];            // [px][oc] f16, 4.6 KB
  __shared__ unsigned short meta_o[576];    // top-left slot per (k,px)
  __shared__ short meta_w[576 * 4];         // 4 folded corner weights f16

  int t = threadIdx.x;
  int x0 = blockIdx.x * 16, y0 = blockIdx.y * 4, b = blockIdx.z;
  int w = t >> 6, lane = t & 63, q = lane >> 4, m = lane & 15;
  int ybase = y0 - 3, xbase = x0 - 3;

  // ---- stage tile (coalesced b128 copies) ----
  const short* xb = xcl + (size_t)b * HWSZ * 64;
  for (int i = t; i < NSLOT * 8; i += 256) {
    int slot = i >> 3, g = i & 7;
    int ty = slot / TC, tx = slot - ty * TC;
    int gy = ybase + ty, gx = xbase + tx;
    short8 v = {};
    if (gy >= 0 && gy < HH && gx >= 0 && gx < WW)
      v = *(const short8*)&xb[(gy * WW + gx) * 64 + g * 8];
    *(short8*)&xt[slot * 64 + ((g ^ (slot & 7)) << 3)] = v;
  }
  __syncthreads();

  // ---- om GEMM: wave w -> 27 oc x 16 px of row y0+w -> omv ----
  {
    f32x4 oacc0 = {}, oacc1 = {};
#pragma unroll 6
    for (int f = 0; f < 18; f++) {
      int k = f >> 1;
      int ki = k / 3, kj = k - ki * 3;
      int g = (f & 1) * 4 + q;
      int slotb = (w + ki + 2) * TC + (m + kj + 2);
      short8 bv = *(const short8*)&xt[slotb * 64 + ((g ^ (slotb & 7)) << 3)];
      const short* ap = who + (f * 128 + m * 4 + q) * 8;
      short8 a0 = *(const short8*)ap;
      short8 a1 = *(const short8*)(ap + 512);
      union { short8 s8; half8 h; } A0, A1, B;
      A0.s8 = a0; A1.s8 = a1; B.s8 = bv;
      oacc0 = __builtin_amdgcn_mfma_f32_16x16x32_f16(A0.h, B.h, oacc0, 0, 0, 0);
      oacc1 = __builtin_amdgcn_mfma_f32_16x16x32_f16(A1.h, B.h, oacc1, 0, 0, 0);
    }
    int px = w * 16 + m;
#pragma unroll
    for (int mt = 0; mt < 2; mt++) {
      f32x4 oa = mt ? oacc1 : oacc0;
      short4v pv;
#pragma unroll
      for (int r = 0; r < 4; r++) {
        int oc = mt * 16 + q * 4 + r;
        float bb = (oc < 27) ? bias_om[oc] : 0.f;
        pv[r] = f2h(oa[r] + bb);
      }
      *(short4v*)&omv[px * 36 + mt * 16 + q * 4] = pv;
    }
  }
  __syncthreads();

  // ---- meta: per (k,px) top-left slot + 4 folded corner weights ----
  for (int i = t; i < 576; i += 256) {
    int k = i >> 6, px = i & 63;
    int y = y0 + (px >> 4), x = x0 + (px & 15);
    float dy = h2f(omv[px * 36 + 2 * k]);
    float dx = h2f(omv[px * 36 + 2 * k + 1]);
    float ml = h2f(omv[px * 36 + 18 + k]);
    float msk = 1.f / (1.f + __expf(-ml));
    int ki = k / 3, kj = k - ki * 3;
    float py  = (float)(y - 1 + ki) + dy;
    float pxf = (float)(x - 1 + kj) + dx;
    float fy = floorf(py), fx = floorf(pxf);
    float ly = py - fy, lx = pxf - fx;
    int yi0 = (int)fy, xi0 = (int)fx;
    bool vy0 = (yi0 >= 0) & (yi0 < HH), vy1 = (yi0 + 1 >= 0) & (yi0 + 1 < HH);
    bool vx0 = (xi0 >= 0) & (xi0 < WW), vx1 = (xi0 + 1 >= 0) & (xi0 + 1 < WW);
    int ty0 = min(max(yi0 - ybase, 0), TR - 2);
    int tx0 = min(max(xi0 - xbase, 0), TC - 2);
    meta_o[i] = (unsigned short)(ty0 * TC + tx0);
    short4v wv;
    wv[0] = f2h((vy0 & vx0) ? (1.f - ly) * (1.f - lx) * msk : 0.f);
    wv[1] = f2h((vy0 & vx1) ? (1.f - ly) * lx * msk : 0.f);
    wv[2] = f2h((vy1 & vx0) ? ly * (1.f - lx) * msk : 0.f);
    wv[3] = f2h((vy1 & vx1) ? ly * lx * msk : 0.f);
    *(short4v*)&meta_w[i * 4] = wv;
  }
  __syncthreads();

  // ---- main GEMM: 64 oc x 16 px, K=576, bilinear fused into B-frags.
  //      A from global (L1); no barriers in this loop. ----
  f32x4 acc[4] = {};
#pragma unroll 3
  for (int k = 0; k < 9; k++) {
    int mi = k * 64 + w * 16 + m;
    int p00 = meta_o[mi];
    short4v wv = *(const short4v*)&meta_w[mi * 4];
    half2v w00 = bcast_h(wv[0]), w01 = bcast_h(wv[1]);
    half2v w10 = bcast_h(wv[2]), w11 = bcast_h(wv[3]);
    int s00 = p00, s01 = p00 + 1, s10 = p00 + TC, s11 = p00 + TC + 1;
#pragma unroll
    for (int ch = 0; ch < 2; ch++) {
      int g = ch * 4 + q;
      const short* ap = whd + k * 4096 + ch * 2048 + m * 32 + q * 8;
      short8 a0 = *(const short8*)ap;
      short8 a1 = *(const short8*)(ap + 512);
      short8 a2 = *(const short8*)(ap + 1024);
      short8 a3 = *(const short8*)(ap + 1536);
      union { short8 s8; half2v h[4]; } c00, c01, c10, c11, bb;
      c00.s8 = *(const short8*)&xt[s00 * 64 + ((g ^ (s00 & 7)) << 3)];
      c01.s8 = *(const short8*)&xt[s01 * 64 + ((g ^ (s01 & 7)) << 3)];
      c10.s8 = *(const short8*)&xt[s10 * 64 + ((g ^ (s10 & 7)) << 3)];
      c11.s8 = *(const short8*)&xt[s11 * 64 + ((g ^ (s11 & 7)) << 3)];
#pragma unroll
      for (int d = 0; d < 4; d++)
        bb.h[d] = c00.h[d] * w00 + c01.h[d] * w01 + c10.h[d] * w10 +
                  c11.h[d] * w11;
      union { short8 s8; half8 h8; } B, A0, A1, A2, A3;
      B.s8 = bb.s8; A0.s8 = a0; A1.s8 = a1; A2.s8 = a2; A3.s8 = a3;
      acc[0] = __builtin_amdgcn_mfma_f32_16x16x32_f16(A0.h8, B.h8, acc[0], 0, 0, 0);
      acc[1] = __builtin_amdgcn_mfma_f32_16x16x32_f16(A1.h8, B.h8, acc[1], 0, 0, 0);
      acc[2] = __builtin_amdgcn_mfma_f32_16x16x32_f16(A2.h8, B.h8, acc[2], 0, 0, 0);
      acc[3] = __builtin_amdgcn_mfma_f32_16x16x32_f16(A3.h8, B.h8, acc[3], 0, 0, 0);
    }
  }

  // ---- epilogue ----
  // D layout: acc[ot] = oc tile ot; oc = ot*16 + q*4 + r; px col = m, row = w
  int y = y0 + w, x = x0 + m;
  if (out_f32) {  // layer 2: BN + residual + GELU -> f32 NCHW
#pragma unroll
    for (int ot = 0; ot < 4; ot++)
#pragma unroll
      for (int r = 0; r < 4; r++) {
        int oc = ot * 16 + q * 4 + r;
        size_t idx = ((size_t)(b * 64 + oc)) * HWSZ + y * WW + x;
        float v = acc[ot][r] * scale[oc] + shift[oc] + identity[idx];
        v = 0.5f * v * (1.f + erff(v * 0.70710678118654752f));
        out_f32[idx] = v;
      }
  } else {  // layer 1: BN + GELU -> f16 NHWC
    size_t base = ((size_t)b * HWSZ + y * WW + x) * 64;
#pragma unroll
    for (int ot = 0; ot < 4; ot++) {
      short4v pv;
#pragma unroll
      for (int r = 0; r < 4; r++) {
        int oc = ot * 16 + q * 4 + r;
        float v = acc[ot][r] * scale[oc] + shift[oc];
        v = 0.5f * v * (1.f + erff(v * 0.70710678118654752f));
        pv[r] = f2h(v);
      }
      *(short4v*)&out_cl[base + ot * 16 + q * 4] = pv;
    }
  }
}

// ---------------------------------------------------------------------------
extern "C" void kernel_launch(void* const* d_in, const int* in_sizes, int n_in,
                              void* d_out, int out_size, void* d_ws, size_t ws_size,
                              hipStream_t stream) {
  const float* x     = (const float*)d_in[0];
  const float* w_om1 = (const float*)d_in[1];
  const float* b_om1 = (const float*)d_in[2];
  const float* w_d1  = (const float*)d_in[3];
  const float* bn1g  = (const float*)d_in[4];
  const float* bn1b  = (const float*)d_in[5];
  const float* bn1m  = (const float*)d_in[6];
  const float* bn1v  = (const float*)d_in[7];
  const float* w_om2 = (const float*)d_in[8];
  const float* b_om2 = (const float*)d_in[9];
  const float* w_d2  = (const float*)d_in[10];
  const float* bn2g  = (const float*)d_in[11];
  const float* bn2b  = (const float*)d_in[12];
  const float* bn2m  = (const float*)d_in[13];
  const float* bn2v  = (const float*)d_in[14];

  float* ws    = (float*)d_ws;
  float* sc    = ws;                       // 256 f
  short* w1h   = (short*)(ws + 256);       // 36864 halves
  short* w2h   = w1h + 36864;
  short* wo1h  = w2h + 36864;              // 18432 halves
  short* wo2h  = wo1h + 18432;
  short* x_cl  = (short*)(ws + 55552);     // 6,553,600 halves
  short* o1_cl = x_cl + 6553600;           // 6,553,600 halves
  float* outp  = (float*)d_out;

  prep_kernel<<<dim3(64), dim3(256), 0, stream>>>(
      bn1g, bn1b, bn1m, bn1v, bn2g, bn2b, bn2m, bn2v,
      w_d1, w_d2, w_om1, w_om2, sc, w1h, w2h, wo1h, wo2h);
  xcl_kernel<<<dim3(HWSZ / 64, 4), dim3(256), 0, stream>>>(x, x_cl);

  dim3 grid(WW / 16, HH / 4, 4);
  dcn_fused<<<grid, dim3(256), 0, stream>>>(
      x_cl, wo1h, b_om1, w1h, sc, sc + 64, nullptr, o1_cl, nullptr);
  dcn_fused<<<grid, dim3(256), 0, stream>>>(
      o1_cl, wo2h, b_om2, w2h, sc + 128, sc + 192, x, nullptr, outp);
}

// Round 10
// 209.592 us; speedup vs baseline: 1.0987x; 1.0987x over previous
//
#include <hip/hip_runtime.h>
#include <math.h>

#define HH 160
#define WW 160
#define HWSZ 25600
#define TR 10
#define TC 22
#define NSLOT 220   // TR*TC tile slots, margin +-3 around 16x4 px tile

typedef __attribute__((ext_vector_type(8))) short short8;
typedef __attribute__((ext_vector_type(4))) short short4v;
typedef __attribute__((ext_vector_type(8))) _Float16 half8;
typedef __attribute__((ext_vector_type(2))) _Float16 half2v;
typedef __attribute__((ext_vector_type(4))) float f32x4;

__device__ __forceinline__ short f2h(float f) {
  union { _Float16 h; short s; } u; u.h = (_Float16)f; return u.s;
}
__device__ __forceinline__ float h2f(short s) {
  union { _Float16 h; short s; } u; u.s = s; return (float)u.h;
}
__device__ __forceinline__ half2v bcast_h(short s) {
  unsigned int x = (unsigned short)s; x |= x << 16;
  union { unsigned int u; half2v h; } v; v.u = x; return v.h;
}

// ---------------------------------------------------------------------------
// pre: blocks [0,1600): transpose x f32 NCHW -> f16 NHWC (verbatim xcl code).
//      blocks [1600,1664): BN fold + weight reorder (verbatim prep code).
// dcn w: [f18][ot4][m16][q4][j8] = w[ot*16+m][c*9+k], kp=f*32+q*8+j
// om  w: [f18][ot2][m16][q4][j8], oc>=27 zero-padded
__global__ __launch_bounds__(256) void pre_kernel(
    const float* __restrict__ x,
    const float* __restrict__ g1, const float* __restrict__ b1,
    const float* __restrict__ m1, const float* __restrict__ v1,
    const float* __restrict__ g2, const float* __restrict__ b2,
    const float* __restrict__ m2, const float* __restrict__ v2,
    const float* __restrict__ wd1, const float* __restrict__ wd2,
    const float* __restrict__ wo1, const float* __restrict__ wo2,
    float* __restrict__ sc, short* __restrict__ wd1h, short* __restrict__ wd2h,
    short* __restrict__ wo1h, short* __restrict__ wo2h,
    short* __restrict__ xcl) {
  __shared__ short tmp[64][72];
  int t = threadIdx.x;
  int bx = blockIdx.x;
  if (bx < 1600) {
    int b = bx / 400, p0 = (bx - b * 400) * 64;
    const float* xb = x + (size_t)b * 64 * HWSZ;
    for (int i = t; i < 4096; i += 256) {
      int c = i >> 6, p = i & 63;
      tmp[p][c] = f2h(xb[c * HWSZ + p0 + p]);
    }
    __syncthreads();
    short* ob = xcl + ((size_t)b * HWSZ + p0) * 64;
    for (int i = t; i < 512; i += 256) {
      int p = i >> 3, g = i & 7;
      *(short8*)&ob[p * 64 + g * 8] = *(const short8*)&tmp[p][g * 8];
    }
    return;
  }
  int i0 = (bx - 1600) * 256 + t;  // 0..16383
  for (int i = i0; i < 36864; i += 16384) {
    int j = i & 7, q = (i >> 3) & 3, m = (i >> 5) & 15;
    int ot = (i >> 9) & 3, f = i >> 11;
    int kp = f * 32 + q * 8 + j;
    int k = kp >> 6, c = kp & 63;
    int src = (ot * 16 + m) * 576 + c * 9 + k;
    wd1h[i] = f2h(wd1[src]);
    wd2h[i] = f2h(wd2[src]);
  }
  for (int i = i0; i < 18432; i += 16384) {
    int j = i & 7, q = (i >> 3) & 3, m = (i >> 5) & 15;
    int ot = (i >> 9) & 1, f = i >> 10;
    int kp = f * 32 + q * 8 + j;
    int k = kp >> 6, c = kp & 63;
    int oc = ot * 16 + m;
    wo1h[i] = (oc < 27) ? f2h(wo1[oc * 576 + c * 9 + k]) : (short)0;
    wo2h[i] = (oc < 27) ? f2h(wo2[oc * 576 + c * 9 + k]) : (short)0;
  }
  if (i0 < 64) {
    float s1 = g1[i0] * rsqrtf(v1[i0] + 1e-5f);
    sc[i0]       = s1;
    sc[64 + i0]  = b1[i0] - m1[i0] * s1;
    float s2 = g2[i0] * rsqrtf(v2[i0] + 1e-5f);
    sc[128 + i0] = s2;
    sc[192 + i0] = b2[i0] - m2[i0] * s2;
  }
}

// ---------------------------------------------------------------------------
// dcn_fused: offset-conv (27ch) + modulated deform conv (64->64) + BN
//            + optional residual + GELU, all from one staged tile.
// Block: 16x * 4y px, 256 thr / 4 waves. Wave w owns pixel row y0+w.
// Main-loop A-weights staged per-tap through LDS (As). Structure identical
// to the R7 kernel that passed at absmax 0.031 / 67.8 us.
__global__ __launch_bounds__(256, 3) void dcn_fused(
    const short* __restrict__ xcl,     // [B][HW][64] f16 NHWC
    const short* __restrict__ who,     // om weights  [f][2][16][4][8]
    const float* __restrict__ bias_om, // 27
    const short* __restrict__ whd,     // dcn weights [f][4][16][4][8]
    const float* __restrict__ scale, const float* __restrict__ shift,
    const short* __restrict__ id_cl,     // f16 NHWC residual or null
    short* __restrict__ out_cl,          // f16 NHWC (layer 1) or null
    float* __restrict__ out_f32) {       // f32 NCHW (layer 2) or null
  __shared__ short xt[NSLOT * 64];          // 28.2 KB, 16B groups swizzled
  __shared__ short omv[64 * 36];            // [px][oc] f16, 4.6 KB
  __shared__ unsigned short meta_o[576];    // top-left slot per (k,px)
  __shared__ short meta_w[576 * 4];         // 4 folded corner weights f16
  __shared__ __align__(16) short As[4096];  // per-tap A panels f=2k,2k+1 (8KB)

  int t = threadIdx.x;
  int x0 = blockIdx.x * 16, y0 = blockIdx.y * 4, b = blockIdx.z;
  int w = t >> 6, lane = t & 63, q = lane >> 4, m = lane & 15;
  int ybase = y0 - 3, xbase = x0 - 3;

  // ---- stage tile (coalesced b128 copies) ----
  const short* xb = xcl + (size_t)b * HWSZ * 64;
  for (int i = t; i < NSLOT * 8; i += 256) {
    int slot = i >> 3, g = i & 7;
    int ty = slot / TC, tx = slot - ty * TC;
    int gy = ybase + ty, gx = xbase + tx;
    short8 v = {};
    if (gy >= 0 && gy < HH && gx >= 0 && gx < WW)
      v = *(const short8*)&xb[(gy * WW + gx) * 64 + g * 8];
    *(short8*)&xt[slot * 64 + ((g ^ (slot & 7)) << 3)] = v;
  }
  __syncthreads();

  // ---- om GEMM: wave w -> 27 oc x 16 px of row y0+w -> omv ----
  {
    f32x4 oacc0 = {}, oacc1 = {};
#pragma unroll 6
    for (int f = 0; f < 18; f++) {
      int k = f >> 1;
      int ki = k / 3, kj = k - ki * 3;
      int g = (f & 1) * 4 + q;
      int slotb = (w + ki + 2) * TC + (m + kj + 2);
      short8 bv = *(const short8*)&xt[slotb * 64 + ((g ^ (slotb & 7)) << 3)];
      const short* ap = who + (f * 128 + m * 4 + q) * 8;
      short8 a0 = *(const short8*)ap;
      short8 a1 = *(const short8*)(ap + 512);
      union { short8 s8; half8 h; } A0, A1, B;
      A0.s8 = a0; A1.s8 = a1; B.s8 = bv;
      oacc0 = __builtin_amdgcn_mfma_f32_16x16x32_f16(A0.h, B.h, oacc0, 0, 0, 0);
      oacc1 = __builtin_amdgcn_mfma_f32_16x16x32_f16(A1.h, B.h, oacc1, 0, 0, 0);
    }
    int px = w * 16 + m;
#pragma unroll
    for (int mt = 0; mt < 2; mt++) {
      f32x4 oa = mt ? oacc1 : oacc0;
      short4v pv;
#pragma unroll
      for (int r = 0; r < 4; r++) {
        int oc = mt * 16 + q * 4 + r;
        float bb = (oc < 27) ? bias_om[oc] : 0.f;
        pv[r] = f2h(oa[r] + bb);
      }
      *(short4v*)&omv[px * 36 + mt * 16 + q * 4] = pv;
    }
  }
  __syncthreads();

  // ---- meta: per (k,px) top-left slot + 4 folded corner weights ----
  for (int i = t; i < 576; i += 256) {
    int k = i >> 6, px = i & 63;
    int y = y0 + (px >> 4), x = x0 + (px & 15);
    float dy = h2f(omv[px * 36 + 2 * k]);
    float dx = h2f(omv[px * 36 + 2 * k + 1]);
    float ml = h2f(omv[px * 36 + 18 + k]);
    float msk = 1.f / (1.f + __expf(-ml));
    int ki = k / 3, kj = k - ki * 3;
    float py  = (float)(y - 1 + ki) + dy;
    float pxf = (float)(x - 1 + kj) + dx;
    float fy = floorf(py), fx = floorf(pxf);
    float ly = py - fy, lx = pxf - fx;
    int yi0 = (int)fy, xi0 = (int)fx;
    bool vy0 = (yi0 >= 0) & (yi0 < HH), vy1 = (yi0 + 1 >= 0) & (yi0 + 1 < HH);
    bool vx0 = (xi0 >= 0) & (xi0 < WW), vx1 = (xi0 + 1 >= 0) & (xi0 + 1 < WW);
    int ty0 = min(max(yi0 - ybase, 0), TR - 2);
    int tx0 = min(max(xi0 - xbase, 0), TC - 2);
    meta_o[i] = (unsigned short)(ty0 * TC + tx0);
    short4v wv;
    wv[0] = f2h((vy0 & vx0) ? (1.f - ly) * (1.f - lx) * msk : 0.f);
    wv[1] = f2h((vy0 & vx1) ? (1.f - ly) * lx * msk : 0.f);
    wv[2] = f2h((vy1 & vx0) ? ly * (1.f - lx) * msk : 0.f);
    wv[3] = f2h((vy1 & vx1) ? ly * lx * msk : 0.f);
    *(short4v*)&meta_w[i * 4] = wv;
  }
  __syncthreads();

  // ---- main GEMM: 64 oc x 16 px, K=576, bilinear fused into B-frags.
  //      A panel for tap k (f=2k,2k+1; 4096 shorts) staged in LDS. ----
  f32x4 acc[4] = {};
  for (int k = 0; k < 9; k++) {
    __syncthreads();  // prior tap's As readers done
    {
      int i = t * 16;
      *(short8*)&As[i]     = *(const short8*)&whd[k * 4096 + i];
      *(short8*)&As[i + 8] = *(const short8*)&whd[k * 4096 + i + 8];
    }
    __syncthreads();  // As visible

    int mi = k * 64 + w * 16 + m;
    int p00 = meta_o[mi];
    short4v wv = *(const short4v*)&meta_w[mi * 4];
    half2v w00 = bcast_h(wv[0]), w01 = bcast_h(wv[1]);
    half2v w10 = bcast_h(wv[2]), w11 = bcast_h(wv[3]);
    int s00 = p00, s01 = p00 + 1, s10 = p00 + TC, s11 = p00 + TC + 1;
#pragma unroll
    for (int ch = 0; ch < 2; ch++) {
      int g = ch * 4 + q;
      const short* ap = As + ch * 2048 + m * 32 + q * 8;
      short8 a0 = *(const short8*)ap;
      short8 a1 = *(const short8*)(ap + 512);
      short8 a2 = *(const short8*)(ap + 1024);
      short8 a3 = *(const short8*)(ap + 1536);
      union { short8 s8; half2v h[4]; } c00, c01, c10, c11, bb;
      c00.s8 = *(const short8*)&xt[s00 * 64 + ((g ^ (s00 & 7)) << 3)];
      c01.s8 = *(const short8*)&xt[s01 * 64 + ((g ^ (s01 & 7)) << 3)];
      c10.s8 = *(const short8*)&xt[s10 * 64 + ((g ^ (s10 & 7)) << 3)];
      c11.s8 = *(const short8*)&xt[s11 * 64 + ((g ^ (s11 & 7)) << 3)];
#pragma unroll
      for (int d = 0; d < 4; d++)
        bb.h[d] = c00.h[d] * w00 + c01.h[d] * w01 + c10.h[d] * w10 +
                  c11.h[d] * w11;
      union { short8 s8; half8 h8; } B, A0, A1, A2, A3;
      B.s8 = bb.s8; A0.s8 = a0; A1.s8 = a1; A2.s8 = a2; A3.s8 = a3;
      acc[0] = __builtin_amdgcn_mfma_f32_16x16x32_f16(A0.h8, B.h8, acc[0], 0, 0, 0);
      acc[1] = __builtin_amdgcn_mfma_f32_16x16x32_f16(A1.h8, B.h8, acc[1], 0, 0, 0);
      acc[2] = __builtin_amdgcn_mfma_f32_16x16x32_f16(A2.h8, B.h8, acc[2], 0, 0, 0);
      acc[3] = __builtin_amdgcn_mfma_f32_16x16x32_f16(A3.h8, B.h8, acc[3], 0, 0, 0);
    }
  }

  // ---- epilogue ----
  // D layout: acc[ot] = oc tile ot; oc = ot*16 + q*4 + r; px col = m, row = w
  int y = y0 + w, x = x0 + m;
  if (out_f32) {  // layer 2: BN + residual (f16 NHWC) + GELU -> f32 NCHW
    size_t pbase = ((size_t)b * HWSZ + y * WW + x) * 64;
#pragma unroll
    for (int ot = 0; ot < 4; ot++) {
      short4v iv = *(const short4v*)&id_cl[pbase + ot * 16 + q * 4];
#pragma unroll
      for (int r = 0; r < 4; r++) {
        int oc = ot * 16 + q * 4 + r;
        size_t idx = ((size_t)(b * 64 + oc)) * HWSZ + y * WW + x;
        float v = acc[ot][r] * scale[oc] + shift[oc] + h2f(iv[r]);
        v = 0.5f * v * (1.f + erff(v * 0.70710678118654752f));
        out_f32[idx] = v;
      }
    }
  } else {  // layer 1: BN + GELU -> f16 NHWC
    size_t base = ((size_t)b * HWSZ + y * WW + x) * 64;
#pragma unroll
    for (int ot = 0; ot < 4; ot++) {
      short4v pv;
#pragma unroll
      for (int r = 0; r < 4; r++) {
        int oc = ot * 16 + q * 4 + r;
        float v = acc[ot][r] * scale[oc] + shift[oc];
        v = 0.5f * v * (1.f + erff(v * 0.70710678118654752f));
        pv[r] = f2h(v);
      }
      *(short4v*)&out_cl[base + ot * 16 + q * 4] = pv;
    }
  }
}

// ---------------------------------------------------------------------------
extern "C" void kernel_launch(void* const* d_in, const int* in_sizes, int n_in,
                              void* d_out, int out_size, void* d_ws, size_t ws_size,
                              hipStream_t stream) {
  const float* x     = (const float*)d_in[0];
  const float* w_om1 = (const float*)d_in[1];
  const float* b_om1 = (const float*)d_in[2];
  const float* w_d1  = (const float*)d_in[3];
  const float* bn1g  = (const float*)d_in[4];
  const float* bn1b  = (const float*)d_in[5];
  const float* bn1m  = (const float*)d_in[6];
  const float* bn1v  = (const float*)d_in[7];
  const float* w_om2 = (const float*)d_in[8];
  const float* b_om2 = (const float*)d_in[9];
  const float* w_d2  = (const float*)d_in[10];
  const float* bn2g  = (const float*)d_in[11];
  const float* bn2b  = (const float*)d_in[12];
  const float* bn2m  = (const float*)d_in[13];
  const float* bn2v  = (const float*)d_in[14];

  float* ws    = (float*)d_ws;
  float* sc    = ws;                       // 256 f
  short* w1h   = (short*)(ws + 256);       // 36864 halves
  short* w2h   = w1h + 36864;
  short* wo1h  = w2h + 36864;              // 18432 halves
  short* wo2h  = wo1h + 18432;
  short* x_cl  = (short*)(ws + 55552);     // 6,553,600 halves
  short* o1_cl = x_cl + 6553600;           // 6,553,600 halves
  float* outp  = (float*)d_out;

  pre_kernel<<<dim3(1664), dim3(256), 0, stream>>>(
      x, bn1g, bn1b, bn1m, bn1v, bn2g, bn2b, bn2m, bn2v,
      w_d1, w_d2, w_om1, w_om2, sc, w1h, w2h, wo1h, wo2h, x_cl);

  dim3 grid(WW / 16, HH / 4, 4);
  dcn_fused<<<grid, dim3(256), 0, stream>>>(
      x_cl, wo1h, b_om1, w1h, sc, sc + 64, nullptr, o1_cl, nullptr);
  dcn_fused<<<grid, dim3(256), 0, stream>>>(
      o1_cl, wo2h, b_om2, w2h, sc + 128, sc + 192, x_cl, nullptr, outp);
}

// Round 11
// 206.705 us; speedup vs baseline: 1.1140x; 1.0140x over previous
//
#include <hip/hip_runtime.h>
#include <math.h>

#define HH 160
#define WW 160
#define HWSZ 25600
#define TR 10
#define TC 22
#define NSLOT 220   // TR*TC tile slots, margin +-3 around 16x4 px tile

typedef __attribute__((ext_vector_type(8))) short short8;
typedef __attribute__((ext_vector_type(4))) short short4v;
typedef __attribute__((ext_vector_type(8))) _Float16 half8;
typedef __attribute__((ext_vector_type(2))) _Float16 half2v;
typedef __attribute__((ext_vector_type(4))) float f32x4;

__device__ __forceinline__ short f2h(float f) {
  union { _Float16 h; short s; } u; u.h = (_Float16)f; return u.s;
}
__device__ __forceinline__ float h2f(short s) {
  union { _Float16 h; short s; } u; u.s = s; return (float)u.h;
}
__device__ __forceinline__ half2v bcast_h(short s) {
  unsigned int x = (unsigned short)s; x |= x << 16;
  union { unsigned int u; half2v h; } v; v.u = x; return v.h;
}

// ---------------------------------------------------------------------------
// pre: blocks [0,1600): transpose x f32 NCHW -> f16 NHWC.
//      blocks [1600,1664): BN fold + weight reorder to A-frag layout.
// dcn w: [f18][ot4][m16][q4][j8] = w[ot*16+m][c*9+k], kp=f*32+q*8+j
// om  w: [f18][ot2][m16][q4][j8], oc>=27 zero-padded
__global__ __launch_bounds__(256) void pre_kernel(
    const float* __restrict__ x,
    const float* __restrict__ g1, const float* __restrict__ b1,
    const float* __restrict__ m1, const float* __restrict__ v1,
    const float* __restrict__ g2, const float* __restrict__ b2,
    const float* __restrict__ m2, const float* __restrict__ v2,
    const float* __restrict__ wd1, const float* __restrict__ wd2,
    const float* __restrict__ wo1, const float* __restrict__ wo2,
    float* __restrict__ sc, short* __restrict__ wd1h, short* __restrict__ wd2h,
    short* __restrict__ wo1h, short* __restrict__ wo2h,
    short* __restrict__ xcl) {
  __shared__ short tmp[64][72];
  int t = threadIdx.x;
  int bx = blockIdx.x;
  if (bx < 1600) {
    int b = bx / 400, p0 = (bx - b * 400) * 64;
    const float* xb = x + (size_t)b * 64 * HWSZ;
    for (int i = t; i < 4096; i += 256) {
      int c = i >> 6, p = i & 63;
      tmp[p][c] = f2h(xb[c * HWSZ + p0 + p]);
    }
    __syncthreads();
    short* ob = xcl + ((size_t)b * HWSZ + p0) * 64;
    for (int i = t; i < 512; i += 256) {
      int p = i >> 3, g = i & 7;
      *(short8*)&ob[p * 64 + g * 8] = *(const short8*)&tmp[p][g * 8];
    }
    return;
  }
  int i0 = (bx - 1600) * 256 + t;  // 0..16383
  for (int i = i0; i < 36864; i += 16384) {
    int j = i & 7, q = (i >> 3) & 3, m = (i >> 5) & 15;
    int ot = (i >> 9) & 3, f = i >> 11;
    int kp = f * 32 + q * 8 + j;
    int k = kp >> 6, c = kp & 63;
    int src = (ot * 16 + m) * 576 + c * 9 + k;
    wd1h[i] = f2h(wd1[src]);
    wd2h[i] = f2h(wd2[src]);
  }
  for (int i = i0; i < 18432; i += 16384) {
    int j = i & 7, q = (i >> 3) & 3, m = (i >> 5) & 15;
    int ot = (i >> 9) & 1, f = i >> 10;
    int kp = f * 32 + q * 8 + j;
    int k = kp >> 6, c = kp & 63;
    int oc = ot * 16 + m;
    wo1h[i] = (oc < 27) ? f2h(wo1[oc * 576 + c * 9 + k]) : (short)0;
    wo2h[i] = (oc < 27) ? f2h(wo2[oc * 576 + c * 9 + k]) : (short)0;
  }
  if (i0 < 64) {
    float s1 = g1[i0] * rsqrtf(v1[i0] + 1e-5f);
    sc[i0]       = s1;
    sc[64 + i0]  = b1[i0] - m1[i0] * s1;
    float s2 = g2[i0] * rsqrtf(v2[i0] + 1e-5f);
    sc[128 + i0] = s2;
    sc[192 + i0] = b2[i0] - m2[i0] * s2;
  }
}

// ---------------------------------------------------------------------------
// dcn_fused: offset-conv (27ch) + modulated deform conv (64->64) + BN
//            + optional residual + GELU, all from one staged tile.
// Block: 16x * 4y px, 256 thr / 4 waves. Wave w owns pixel row y0+w.
// A panels double-buffered in LDS: 1 barrier/tap, reg-prefetch of tap k+1
// issued before compute-k (global latency hidden). omv aliases As buf1.
__global__ __launch_bounds__(256, 3) void dcn_fused(
    const short* __restrict__ xcl,     // [B][HW][64] f16 NHWC
    const short* __restrict__ who,     // om weights  [f][2][16][4][8]
    const float* __restrict__ bias_om, // 27
    const short* __restrict__ whd,     // dcn weights [f][4][16][4][8]
    const float* __restrict__ scale, const float* __restrict__ shift,
    const short* __restrict__ id_cl,     // f16 NHWC residual or null
    short* __restrict__ out_cl,          // f16 NHWC (layer 1) or null
    float* __restrict__ out_f32) {       // f32 NCHW (layer 2) or null
  __shared__ short xt[NSLOT * 64];           // 28.2 KB, 16B groups swizzled
  __shared__ __align__(16) short Asb[2][4096]; // A dbuf 16 KB; buf1 aliases omv
  __shared__ unsigned short meta_o[576];     // top-left slot per (k,px)
  __shared__ short meta_w[576 * 4];          // 4 folded corner weights f16
  short* omv = &Asb[1][0];  // 64 px * 36 oc f16 during om phase (2304 shorts)

  int t = threadIdx.x;
  int x0 = blockIdx.x * 16, y0 = blockIdx.y * 4, b = blockIdx.z;
  int w = t >> 6, lane = t & 63, q = lane >> 4, m = lane & 15;
  int ybase = y0 - 3, xbase = x0 - 3;

  // early-issue global loads of tap-0 A panel (completes during staging/om)
  short8 pr0 = *(const short8*)&whd[t * 8];
  short8 pr1 = *(const short8*)&whd[2048 + t * 8];

  // ---- stage tile (coalesced b128 copies) ----
  const short* xb = xcl + (size_t)b * HWSZ * 64;
  for (int i = t; i < NSLOT * 8; i += 256) {
    int slot = i >> 3, g = i & 7;
    int ty = slot / TC, tx = slot - ty * TC;
    int gy = ybase + ty, gx = xbase + tx;
    short8 v = {};
    if (gy >= 0 && gy < HH && gx >= 0 && gx < WW)
      v = *(const short8*)&xb[(gy * WW + gx) * 64 + g * 8];
    *(short8*)&xt[slot * 64 + ((g ^ (slot & 7)) << 3)] = v;
  }
  __syncthreads();

  // ---- om GEMM: wave w -> 27 oc x 16 px of row y0+w -> omv ----
  {
    f32x4 oacc0 = {}, oacc1 = {};
#pragma unroll 6
    for (int f = 0; f < 18; f++) {
      int k = f >> 1;
      int ki = k / 3, kj = k - ki * 3;
      int g = (f & 1) * 4 + q;
      int slotb = (w + ki + 2) * TC + (m + kj + 2);
      short8 bv = *(const short8*)&xt[slotb * 64 + ((g ^ (slotb & 7)) << 3)];
      const short* ap = who + (f * 128 + m * 4 + q) * 8;
      short8 a0 = *(const short8*)ap;
      short8 a1 = *(const short8*)(ap + 512);
      union { short8 s8; half8 h; } A0, A1, B;
      A0.s8 = a0; A1.s8 = a1; B.s8 = bv;
      oacc0 = __builtin_amdgcn_mfma_f32_16x16x32_f16(A0.h, B.h, oacc0, 0, 0, 0);
      oacc1 = __builtin_amdgcn_mfma_f32_16x16x32_f16(A1.h, B.h, oacc1, 0, 0, 0);
    }
    int px = w * 16 + m;
#pragma unroll
    for (int mt = 0; mt < 2; mt++) {
      f32x4 oa = mt ? oacc1 : oacc0;
      short4v pv;
#pragma unroll
      for (int r = 0; r < 4; r++) {
        int oc = mt * 16 + q * 4 + r;
        float bb = (oc < 27) ? bias_om[oc] : 0.f;
        pv[r] = f2h(oa[r] + bb);
      }
      *(short4v*)&omv[px * 36 + mt * 16 + q * 4] = pv;
    }
  }
  __syncthreads();

  // ---- meta: per (k,px) top-left slot + 4 folded corner weights.
  //      Also: write tap-0 A panel into As buf0 (independent of meta). ----
  *(short8*)&Asb[0][t * 8]        = pr0;
  *(short8*)&Asb[0][2048 + t * 8] = pr1;
  for (int i = t; i < 576; i += 256) {
    int k = i >> 6, px = i & 63;
    int y = y0 + (px >> 4), x = x0 + (px & 15);
    float dy = h2f(omv[px * 36 + 2 * k]);
    float dx = h2f(omv[px * 36 + 2 * k + 1]);
    float ml = h2f(omv[px * 36 + 18 + k]);
    float msk = 1.f / (1.f + __expf(-ml));
    int ki = k / 3, kj = k - ki * 3;
    float py  = (float)(y - 1 + ki) + dy;
    float pxf = (float)(x - 1 + kj) + dx;
    float fy = floorf(py), fx = floorf(pxf);
    float ly = py - fy, lx = pxf - fx;
    int yi0 = (int)fy, xi0 = (int)fx;
    bool vy0 = (yi0 >= 0) & (yi0 < HH), vy1 = (yi0 + 1 >= 0) & (yi0 + 1 < HH);
    bool vx0 = (xi0 >= 0) & (xi0 < WW), vx1 = (xi0 + 1 >= 0) & (xi0 + 1 < WW);
    int ty0 = min(max(yi0 - ybase, 0), TR - 2);
    int tx0 = min(max(xi0 - xbase, 0), TC - 2);
    meta_o[i] = (unsigned short)(ty0 * TC + tx0);
    short4v wv;
    wv[0] = f2h((vy0 & vx0) ? (1.f - ly) * (1.f - lx) * msk : 0.f);
    wv[1] = f2h((vy0 & vx1) ? (1.f - ly) * lx * msk : 0.f);
    wv[2] = f2h((vy1 & vx0) ? ly * (1.f - lx) * msk : 0.f);
    wv[3] = f2h((vy1 & vx1) ? ly * lx * msk : 0.f);
    *(short4v*)&meta_w[i * 4] = wv;
  }
  __syncthreads();  // meta + As buf0 visible; omv dead -> buf1 reusable

  // ---- main GEMM: 64 oc x 16 px, K=576, bilinear fused into B-frags.
  //      A double-buffered in LDS; 1 barrier/tap; prefetch k+1 in regs. ----
  f32x4 acc[4] = {};
  for (int k = 0; k < 9; k++) {
    if (k < 8) {  // issue next tap's A loads; complete during compute below
      pr0 = *(const short8*)&whd[(k + 1) * 4096 + t * 8];
      pr1 = *(const short8*)&whd[(k + 1) * 4096 + 2048 + t * 8];
    }
    const short* As = &Asb[k & 1][0];

    int mi = k * 64 + w * 16 + m;
    int p00 = meta_o[mi];
    short4v wv = *(const short4v*)&meta_w[mi * 4];
    half2v w00 = bcast_h(wv[0]), w01 = bcast_h(wv[1]);
    half2v w10 = bcast_h(wv[2]), w11 = bcast_h(wv[3]);
    int s00 = p00, s01 = p00 + 1, s10 = p00 + TC, s11 = p00 + TC + 1;
#pragma unroll
    for (int ch = 0; ch < 2; ch++) {
      int g = ch * 4 + q;
      const short* ap = As + ch * 2048 + m * 32 + q * 8;
      short8 a0 = *(const short8*)ap;
      short8 a1 = *(const short8*)(ap + 512);
      short8 a2 = *(const short8*)(ap + 1024);
      short8 a3 = *(const short8*)(ap + 1536);
      union { short8 s8; half2v h[4]; } c00, c01, c10, c11, bb;
      c00.s8 = *(const short8*)&xt[s00 * 64 + ((g ^ (s00 & 7)) << 3)];
      c01.s8 = *(const short8*)&xt[s01 * 64 + ((g ^ (s01 & 7)) << 3)];
      c10.s8 = *(const short8*)&xt[s10 * 64 + ((g ^ (s10 & 7)) << 3)];
      c11.s8 = *(const short8*)&xt[s11 * 64 + ((g ^ (s11 & 7)) << 3)];
#pragma unroll
      for (int d = 0; d < 4; d++)
        bb.h[d] = c00.h[d] * w00 + c01.h[d] * w01 + c10.h[d] * w10 +
                  c11.h[d] * w11;
      union { short8 s8; half8 h8; } B, A0, A1, A2, A3;
      B.s8 = bb.s8; A0.s8 = a0; A1.s8 = a1; A2.s8 = a2; A3.s8 = a3;
      acc[0] = __builtin_amdgcn_mfma_f32_16x16x32_f16(A0.h8, B.h8, acc[0], 0, 0, 0);
      acc[1] = __builtin_amdgcn_mfma_f32_16x16x32_f16(A1.h8, B.h8, acc[1], 0, 0, 0);
      acc[2] = __builtin_amdgcn_mfma_f32_16x16x32_f16(A2.h8, B.h8, acc[2], 0, 0, 0);
      acc[3] = __builtin_amdgcn_mfma_f32_16x16x32_f16(A3.h8, B.h8, acc[3], 0, 0, 0);
    }

    if (k < 8) {  // stage tap k+1 into the other buffer; single barrier
      *(short8*)&Asb[(k + 1) & 1][t * 8]        = pr0;
      *(short8*)&Asb[(k + 1) & 1][2048 + t * 8] = pr1;
      __syncthreads();
    }
  }

  // ---- epilogue ----
  // D layout: acc[ot] = oc tile ot; oc = ot*16 + q*4 + r; px col = m, row = w
  int y = y0 + w, x = x0 + m;
  if (out_f32) {  // layer 2: BN + residual (f16 NHWC) + GELU -> f32 NCHW
    size_t pbase = ((size_t)b * HWSZ + y * WW + x) * 64;
#pragma unroll
    for (int ot = 0; ot < 4; ot++) {
      short4v iv = *(const short4v*)&id_cl[pbase + ot * 16 + q * 4];
#pragma unroll
      for (int r = 0; r < 4; r++) {
        int oc = ot * 16 + q * 4 + r;
        size_t idx = ((size_t)(b * 64 + oc)) * HWSZ + y * WW + x;
        float v = acc[ot][r] * scale[oc] + shift[oc] + h2f(iv[r]);
        v = 0.5f * v * (1.f + erff(v * 0.70710678118654752f));
        out_f32[idx] = v;
      }
    }
  } else {  // layer 1: BN + GELU -> f16 NHWC
    size_t base = ((size_t)b * HWSZ + y * WW + x) * 64;
#pragma unroll
    for (int ot = 0; ot < 4; ot++) {
      short4v pv;
#pragma unroll
      for (int r = 0; r < 4; r++) {
        int oc = ot * 16 + q * 4 + r;
        float v = acc[ot][r] * scale[oc] + shift[oc];
        v = 0.5f * v * (1.f + erff(v * 0.70710678118654752f));
        pv[r] = f2h(v);
      }
      *(short4v*)&out_cl[base + ot * 16 + q * 4] = pv;
    }
  }
}

// ---------------------------------------------------------------------------
extern "C" void kernel_launch(void* const* d_in, const int* in_sizes, int n_in,
                              void* d_out, int out_size, void* d_ws, size_t ws_size,
                              hipStream_t stream) {
  const float* x     = (const float*)d_in[0];
  const float* w_om1 = (const float*)d_in[1];
  const float* b_om1 = (const float*)d_in[2];
  const float* w_d1  = (const float*)d_in[3];
  const float* bn1g  = (const float*)d_in[4];
  const float* bn1b  = (const float*)d_in[5];
  const float* bn1m  = (const float*)d_in[6];
  const float* bn1v  = (const float*)d_in[7];
  const float* w_om2 = (const float*)d_in[8];
  const float* b_om2 = (const float*)d_in[9];
  const float* w_d2  = (const float*)d_in[10];
  const float* bn2g  = (const float*)d_in[11];
  const float* bn2b  = (const float*)d_in[12];
  const float* bn2m  = (const float*)d_in[13];
  const float* bn2v  = (const float*)d_in[14];

  float* ws    = (float*)d_ws;
  float* sc    = ws;                       // 256 f
  short* w1h   = (short*)(ws + 256);       // 36864 halves
  short* w2h   = w1h + 36864;
  short* wo1h  = w2h + 36864;              // 18432 halves
  short* wo2h  = wo1h + 18432;
  short* x_cl  = (short*)(ws + 55552);     // 6,553,600 halves
  short* o1_cl = x_cl + 6553600;           // 6,553,600 halves
  float* outp  = (float*)d_out;

  pre_kernel<<<dim3(1664), dim3(256), 0, stream>>>(
      x, bn1g, bn1b, bn1m, bn1v, bn2g, bn2b, bn2m, bn2v,
      w_d1, w_d2, w_om1, w_om2, sc, w1h, w2h, wo1h, wo2h, x_cl);

  dim3 grid(WW / 16, HH / 4, 4);
  dcn_fused<<<grid, dim3(256), 0, stream>>>(
      x_cl, wo1h, b_om1, w1h, sc, sc + 64, nullptr, o1_cl, nullptr);
  dcn_fused<<<grid, dim3(256), 0, stream>>>(
      o1_cl, wo2h, b_om2, w2h, sc + 128, sc + 192, x_cl, nullptr, outp);
}

// Round 12
// 198.311 us; speedup vs baseline: 1.1612x; 1.0423x over previous
//
#include <hip/hip_runtime.h>
#include <math.h>

#define HH 160
#define WW 160
#define HWSZ 25600
#define TR 10
#define TC 22
#define NSLOT 220   // TR*TC tile slots, margin +-3 around 16x4 px tile

typedef __attribute__((ext_vector_type(8))) short short8;
typedef __attribute__((ext_vector_type(4))) short short4v;
typedef __attribute__((ext_vector_type(8))) _Float16 half8;
typedef __attribute__((ext_vector_type(2))) _Float16 half2v;
typedef __attribute__((ext_vector_type(4))) float f32x4;

__device__ __forceinline__ short f2h(float f) {
  union { _Float16 h; short s; } u; u.h = (_Float16)f; return u.s;
}
__device__ __forceinline__ float h2f(short s) {
  union { _Float16 h; short s; } u; u.s = s; return (float)u.h;
}
__device__ __forceinline__ half2v bcast_h(short s) {
  unsigned int x = (unsigned short)s; x |= x << 16;
  union { unsigned int u; half2v h; } v; v.u = x; return v.h;
}

// ---------------------------------------------------------------------------
// pre: blocks [0,1600): transpose x f32 NCHW -> f16 NHWC.
//      blocks [1600,1664): BN fold + weight reorder to A-frag layout.
// dcn w: [f18][ot4][m16][q4][j8] = w[ot*16+m][c*9+k], kp=f*32+q*8+j
// om  w: [f18][ot2][m16][q4][j8], oc>=27 zero-padded
__global__ __launch_bounds__(256) void pre_kernel(
    const float* __restrict__ x,
    const float* __restrict__ g1, const float* __restrict__ b1,
    const float* __restrict__ m1, const float* __restrict__ v1,
    const float* __restrict__ g2, const float* __restrict__ b2,
    const float* __restrict__ m2, const float* __restrict__ v2,
    const float* __restrict__ wd1, const float* __restrict__ wd2,
    const float* __restrict__ wo1, const float* __restrict__ wo2,
    float* __restrict__ sc, short* __restrict__ wd1h, short* __restrict__ wd2h,
    short* __restrict__ wo1h, short* __restrict__ wo2h,
    short* __restrict__ xcl) {
  __shared__ short tmp[64][72];
  int t = threadIdx.x;
  int bx = blockIdx.x;
  if (bx < 1600) {
    int b = bx / 400, p0 = (bx - b * 400) * 64;
    const float* xb = x + (size_t)b * 64 * HWSZ;
    for (int i = t; i < 4096; i += 256) {
      int c = i >> 6, p = i & 63;
      tmp[p][c] = f2h(xb[c * HWSZ + p0 + p]);
    }
    __syncthreads();
    short* ob = xcl + ((size_t)b * HWSZ + p0) * 64;
    for (int i = t; i < 512; i += 256) {
      int p = i >> 3, g = i & 7;
      *(short8*)&ob[p * 64 + g * 8] = *(const short8*)&tmp[p][g * 8];
    }
    return;
  }
  int i0 = (bx - 1600) * 256 + t;  // 0..16383
  for (int i = i0; i < 36864; i += 16384) {
    int j = i & 7, q = (i >> 3) & 3, m = (i >> 5) & 15;
    int ot = (i >> 9) & 3, f = i >> 11;
    int kp = f * 32 + q * 8 + j;
    int k = kp >> 6, c = kp & 63;
    int src = (ot * 16 + m) * 576 + c * 9 + k;
    wd1h[i] = f2h(wd1[src]);
    wd2h[i] = f2h(wd2[src]);
  }
  for (int i = i0; i < 18432; i += 16384) {
    int j = i & 7, q = (i >> 3) & 3, m = (i >> 5) & 15;
    int ot = (i >> 9) & 1, f = i >> 10;
    int kp = f * 32 + q * 8 + j;
    int k = kp >> 6, c = kp & 63;
    int oc = ot * 16 + m;
    wo1h[i] = (oc < 27) ? f2h(wo1[oc * 576 + c * 9 + k]) : (short)0;
    wo2h[i] = (oc < 27) ? f2h(wo2[oc * 576 + c * 9 + k]) : (short)0;
  }
  if (i0 < 64) {
    float s1 = g1[i0] * rsqrtf(v1[i0] + 1e-5f);
    sc[i0]       = s1;
    sc[64 + i0]  = b1[i0] - m1[i0] * s1;
    float s2 = g2[i0] * rsqrtf(v2[i0] + 1e-5f);
    sc[128 + i0] = s2;
    sc[192 + i0] = b2[i0] - m2[i0] * s2;
  }
}

// ---------------------------------------------------------------------------
// dcn_fused: offset-conv (27ch) + modulated deform conv (64->64) + BN
//            + optional residual + GELU, all from one staged tile.
// Block: 16x * 4y px, 256 thr / 4 waves. Wave w owns pixel row y0+w.
// LDS = xt (28.2 KB) + As (8 KB) only -> 4 blocks/CU. om results round-trip
// through As-as-scratch into per-lane registers; sampling meta computed
// inline per tap (each lane is sole consumer of its pixel's meta).
__global__ __launch_bounds__(256, 4) void dcn_fused(
    const short* __restrict__ xcl,     // [B][HW][64] f16 NHWC
    const short* __restrict__ who,     // om weights  [f][2][16][4][8]
    const float* __restrict__ bias_om, // 27
    const short* __restrict__ whd,     // dcn weights [f][4][16][4][8]
    const float* __restrict__ scale, const float* __restrict__ shift,
    const short* __restrict__ id_cl,     // f16 NHWC residual or null
    short* __restrict__ out_cl,          // f16 NHWC (layer 1) or null
    float* __restrict__ out_f32) {       // f32 NCHW (layer 2) or null
  __shared__ short xt[NSLOT * 64];          // 28.2 KB, 16B groups swizzled
  __shared__ __align__(16) short As[4096];  // A panel / om scratch (8 KB)

  int t = threadIdx.x;
  int x0 = blockIdx.x * 16, y0 = blockIdx.y * 4, b = blockIdx.z;
  int w = t >> 6, lane = t & 63, q = lane >> 4, m = lane & 15;
  int ybase = y0 - 3, xbase = x0 - 3;

  // early-issue global loads of tap-0 A panel (completes during staging/om)
  short8 pr0 = *(const short8*)&whd[t * 8];
  short8 pr1 = *(const short8*)&whd[2048 + t * 8];

  // ---- stage tile (coalesced b128 copies) ----
  const short* xb = xcl + (size_t)b * HWSZ * 64;
  for (int i = t; i < NSLOT * 8; i += 256) {
    int slot = i >> 3, g = i & 7;
    int ty = slot / TC, tx = slot - ty * TC;
    int gy = ybase + ty, gx = xbase + tx;
    short8 v = {};
    if (gy >= 0 && gy < HH && gx >= 0 && gx < WW)
      v = *(const short8*)&xb[(gy * WW + gx) * 64 + g * 8];
    *(short8*)&xt[slot * 64 + ((g ^ (slot & 7)) << 3)] = v;
  }
  __syncthreads();

  // ---- om GEMM: wave w -> 27 oc x 16 px of row y0+w -> As scratch ----
  {
    f32x4 oacc0 = {}, oacc1 = {};
#pragma unroll 6
    for (int f = 0; f < 18; f++) {
      int k = f >> 1;
      int ki = k / 3, kj = k - ki * 3;
      int g = (f & 1) * 4 + q;
      int slotb = (w + ki + 2) * TC + (m + kj + 2);
      short8 bv = *(const short8*)&xt[slotb * 64 + ((g ^ (slotb & 7)) << 3)];
      const short* ap = who + (f * 128 + m * 4 + q) * 8;
      short8 a0 = *(const short8*)ap;
      short8 a1 = *(const short8*)(ap + 512);
      union { short8 s8; half8 h; } A0, A1, B;
      A0.s8 = a0; A1.s8 = a1; B.s8 = bv;
      oacc0 = __builtin_amdgcn_mfma_f32_16x16x32_f16(A0.h, B.h, oacc0, 0, 0, 0);
      oacc1 = __builtin_amdgcn_mfma_f32_16x16x32_f16(A1.h, B.h, oacc1, 0, 0, 0);
    }
    int px = w * 16 + m;
#pragma unroll
    for (int mt = 0; mt < 2; mt++) {
      f32x4 oa = mt ? oacc1 : oacc0;
      short4v pv;
#pragma unroll
      for (int r = 0; r < 4; r++) {
        int oc = mt * 16 + q * 4 + r;
        float bb = (oc < 27) ? bias_om[oc] : 0.f;
        pv[r] = f2h(oa[r] + bb);
      }
      *(short4v*)&As[px * 40 + mt * 16 + q * 4] = pv;  // stride 40: 16B-aligned rows
    }
  }
  __syncthreads();

  // ---- pull this lane's pixel om values (36 ch) into registers ----
  union { short s[40]; short8 v[5]; } omr;
  {
    int px = w * 16 + m;
#pragma unroll
    for (int i = 0; i < 5; i++)
      omr.v[i] = *(const short8*)&As[px * 40 + i * 8];
  }

  // ---- main GEMM: 64 oc x 16 px, K=576; A panel single-buffered in LDS
  //      (2 barriers/tap, reg-prefetch of k+1); meta computed inline. ----
  f32x4 acc[4] = {};
#pragma unroll
  for (int k = 0; k < 9; k++) {
    __syncthreads();  // prior tap's As readers (or omr reg loads) done
    *(short8*)&As[t * 8]        = pr0;
    *(short8*)&As[2048 + t * 8] = pr1;
    if (k < 8) {  // issue next tap's A loads; complete during compute below
      pr0 = *(const short8*)&whd[(k + 1) * 4096 + t * 8];
      pr1 = *(const short8*)&whd[(k + 1) * 4096 + 2048 + t * 8];
    }
    __syncthreads();  // As visible

    // inline meta for this lane's pixel (verbatim formulas)
    int y = y0 + w, x = x0 + m;
    float dy = h2f(omr.s[2 * k]);
    float dx = h2f(omr.s[2 * k + 1]);
    float ml = h2f(omr.s[18 + k]);
    float msk = 1.f / (1.f + __expf(-ml));
    int ki = k / 3, kj = k - ki * 3;
    float py  = (float)(y - 1 + ki) + dy;
    float pxf = (float)(x - 1 + kj) + dx;
    float fy = floorf(py), fx = floorf(pxf);
    float ly = py - fy, lx = pxf - fx;
    int yi0 = (int)fy, xi0 = (int)fx;
    bool vy0 = (yi0 >= 0) & (yi0 < HH), vy1 = (yi0 + 1 >= 0) & (yi0 + 1 < HH);
    bool vx0 = (xi0 >= 0) & (xi0 < WW), vx1 = (xi0 + 1 >= 0) & (xi0 + 1 < WW);
    int ty0 = min(max(yi0 - ybase, 0), TR - 2);
    int tx0 = min(max(xi0 - xbase, 0), TC - 2);
    int p00 = ty0 * TC + tx0;
    half2v w00 = bcast_h(f2h((vy0 & vx0) ? (1.f - ly) * (1.f - lx) * msk : 0.f));
    half2v w01 = bcast_h(f2h((vy0 & vx1) ? (1.f - ly) * lx * msk : 0.f));
    half2v w10 = bcast_h(f2h((vy1 & vx0) ? ly * (1.f - lx) * msk : 0.f));
    half2v w11 = bcast_h(f2h((vy1 & vx1) ? ly * lx * msk : 0.f));
    int s00 = p00, s01 = p00 + 1, s10 = p00 + TC, s11 = p00 + TC + 1;
#pragma unroll
    for (int ch = 0; ch < 2; ch++) {
      int g = ch * 4 + q;
      const short* ap = As + ch * 2048 + m * 32 + q * 8;
      short8 a0 = *(const short8*)ap;
      short8 a1 = *(const short8*)(ap + 512);
      short8 a2 = *(const short8*)(ap + 1024);
      short8 a3 = *(const short8*)(ap + 1536);
      union { short8 s8; half2v h[4]; } c00, c01, c10, c11, bb;
      c00.s8 = *(const short8*)&xt[s00 * 64 + ((g ^ (s00 & 7)) << 3)];
      c01.s8 = *(const short8*)&xt[s01 * 64 + ((g ^ (s01 & 7)) << 3)];
      c10.s8 = *(const short8*)&xt[s10 * 64 + ((g ^ (s10 & 7)) << 3)];
      c11.s8 = *(const short8*)&xt[s11 * 64 + ((g ^ (s11 & 7)) << 3)];
#pragma unroll
      for (int d = 0; d < 4; d++)
        bb.h[d] = c00.h[d] * w00 + c01.h[d] * w01 + c10.h[d] * w10 +
                  c11.h[d] * w11;
      union { short8 s8; half8 h8; } B, A0, A1, A2, A3;
      B.s8 = bb.s8; A0.s8 = a0; A1.s8 = a1; A2.s8 = a2; A3.s8 = a3;
      acc[0] = __builtin_amdgcn_mfma_f32_16x16x32_f16(A0.h8, B.h8, acc[0], 0, 0, 0);
      acc[1] = __builtin_amdgcn_mfma_f32_16x16x32_f16(A1.h8, B.h8, acc[1], 0, 0, 0);
      acc[2] = __builtin_amdgcn_mfma_f32_16x16x32_f16(A2.h8, B.h8, acc[2], 0, 0, 0);
      acc[3] = __builtin_amdgcn_mfma_f32_16x16x32_f16(A3.h8, B.h8, acc[3], 0, 0, 0);
    }
  }

  // ---- epilogue ----
  // D layout: acc[ot] = oc tile ot; oc = ot*16 + q*4 + r; px col = m, row = w
  int y = y0 + w, x = x0 + m;
  if (out_f32) {  // layer 2: BN + residual (f16 NHWC) + GELU -> f32 NCHW
    size_t pbase = ((size_t)b * HWSZ + y * WW + x) * 64;
#pragma unroll
    for (int ot = 0; ot < 4; ot++) {
      short4v iv = *(const short4v*)&id_cl[pbase + ot * 16 + q * 4];
#pragma unroll
      for (int r = 0; r < 4; r++) {
        int oc = ot * 16 + q * 4 + r;
        size_t idx = ((size_t)(b * 64 + oc)) * HWSZ + y * WW + x;
        float v = acc[ot][r] * scale[oc] + shift[oc] + h2f(iv[r]);
        v = 0.5f * v * (1.f + erff(v * 0.70710678118654752f));
        out_f32[idx] = v;
      }
    }
  } else {  // layer 1: BN + GELU -> f16 NHWC
    size_t base = ((size_t)b * HWSZ + y * WW + x) * 64;
#pragma unroll
    for (int ot = 0; ot < 4; ot++) {
      short4v pv;
#pragma unroll
      for (int r = 0; r < 4; r++) {
        int oc = ot * 16 + q * 4 + r;
        float v = acc[ot][r] * scale[oc] + shift[oc];
        v = 0.5f * v * (1.f + erff(v * 0.70710678118654752f));
        pv[r] = f2h(v);
      }
      *(short4v*)&out_cl[base + ot * 16 + q * 4] = pv;
    }
  }
}

// ---------------------------------------------------------------------------
extern "C" void kernel_launch(void* const* d_in, const int* in_sizes, int n_in,
                              void* d_out, int out_size, void* d_ws, size_t ws_size,
                              hipStream_t stream) {
  const float* x     = (const float*)d_in[0];
  const float* w_om1 = (const float*)d_in[1];
  const float* b_om1 = (const float*)d_in[2];
  const float* w_d1  = (const float*)d_in[3];
  const float* bn1g  = (const float*)d_in[4];
  const float* bn1b  = (const float*)d_in[5];
  const float* bn1m  = (const float*)d_in[6];
  const float* bn1v  = (const float*)d_in[7];
  const float* w_om2 = (const float*)d_in[8];
  const float* b_om2 = (const float*)d_in[9];
  const float* w_d2  = (const float*)d_in[10];
  const float* bn2g  = (const float*)d_in[11];
  const float* bn2b  = (const float*)d_in[12];
  const float* bn2m  = (const float*)d_in[13];
  const float* bn2v  = (const float*)d_in[14];

  float* ws    = (float*)d_ws;
  float* sc    = ws;                       // 256 f
  short* w1h   = (short*)(ws + 256);       // 36864 halves
  short* w2h   = w1h + 36864;
  short* wo1h  = w2h + 36864;              // 18432 halves
  short* wo2h  = wo1h + 18432;
  short* x_cl  = (short*)(ws + 55552);     // 6,553,600 halves
  short* o1_cl = x_cl + 6553600;           // 6,553,600 halves
  float* outp  = (float*)d_out;

  pre_kernel<<<dim3(1664), dim3(256), 0, stream>>>(
      x, bn1g, bn1b, bn1m, bn1v, bn2g, bn2b, bn2m, bn2v,
      w_d1, w_d2, w_om1, w_om2, sc, w1h, w2h, wo1h, wo2h, x_cl);

  dim3 grid(WW / 16, HH / 4, 4);
  dcn_fused<<<grid, dim3(256), 0, stream>>>(
      x_cl, wo1h, b_om1, w1h, sc, sc + 64, nullptr, o1_cl, nullptr);
  dcn_fused<<<grid, dim3(256), 0, stream>>>(
      o1_cl, wo2h, b_om2, w2h, sc + 128, sc + 192, x_cl, nullptr, outp);
}